// Round 2
// baseline (386.621 us; speedup 1.0000x reference)
//
#include <hip/hip_runtime.h>
#include <math.h>

#define BB 8
#define NCC 1024
#define NTT 1024
#define HH 128
#define DYY 32
#define NCG 8                    /* chunk-groups per batch row */
#define NTG (BB * (NTT / 64))    /* 128 target-groups of 64 */

// ---------------- K1: h1 = relu(xt @ W0 + b0), xt:(8192,3), W0:(3,128) ----------------
__global__ void k_layer0(const float* __restrict__ xt, const float* __restrict__ W0,
                         const float* __restrict__ b0, float* __restrict__ h1) {
    int gid = blockIdx.x * blockDim.x + threadIdx.x;   // 0 .. 8192*128
    int p = gid >> 7, j = gid & 127;
    float x0 = xt[p * 3 + 0], x1 = xt[p * 3 + 1], x2 = xt[p * 3 + 2];
    float acc = b0[j];
    acc = fmaf(W0[0 * HH + j], x0, acc);
    acc = fmaf(W0[1 * HH + j], x1, acc);
    acc = fmaf(W0[2 * HH + j], x2, acc);
    h1[gid] = fmaxf(acc, 0.f);
}

// ---------------- K2: h2 = relu(h1 @ W1 + b1) ----------------
// thread j owns column j; 4 rows/thread (4 indep fma chains); W column held in
// 64 VGPRs per k-half so VGPR<=128 -> 4 waves/SIMD. h-row loads wave-uniform.
__global__ __launch_bounds__(256, 4) void k_layer(const float* __restrict__ hin,
                                                  const float* __restrict__ W,
                                                  const float* __restrict__ bias,
                                                  float* __restrict__ hout) {
    const int j = threadIdx.x & 127;
    const int slot = threadIdx.x >> 7;                 // 0..1
    const int row0 = blockIdx.x * 8 + slot * 4;        // 1024 blocks x 8 rows
    float bj = bias[j];
    float acc0 = bj, acc1 = bj, acc2 = bj, acc3 = bj;
    const float* __restrict__ h0 = hin + (size_t)row0 * HH;
#pragma unroll
    for (int pass = 0; pass < 2; ++pass) {
        float wcol[64];
#pragma unroll
        for (int k = 0; k < 64; ++k) wcol[k] = W[(pass * 64 + k) * HH + j];
#pragma unroll
        for (int k = 0; k < 64; ++k) {
            int kk = pass * 64 + k;
            float w = wcol[k];
            acc0 = fmaf(w, h0[0 * HH + kk], acc0);
            acc1 = fmaf(w, h0[1 * HH + kk], acc1);
            acc2 = fmaf(w, h0[2 * HH + kk], acc2);
            acc3 = fmaf(w, h0[3 * HH + kk], acc3);
        }
    }
    hout[(size_t)(row0 + 0) * HH + j] = fmaxf(acc0, 0.f);
    hout[(size_t)(row0 + 1) * HH + j] = fmaxf(acc1, 0.f);
    hout[(size_t)(row0 + 2) * HH + j] = fmaxf(acc2, 0.f);
    hout[(size_t)(row0 + 3) * HH + j] = fmaxf(acc3, 0.f);
}

// ---------------- K3: h3 = relu(h2 @ W2 + b2); sig = exp(h3 @ W3 + b3) fused ----------------
// Same core as k_layer; epilogue shuffle-reduces layer3 across the 128-thread
// j-team (2 waves) so h3 is never written to global.
__global__ __launch_bounds__(256, 4) void k_layer2sig(const float* __restrict__ hin,
                                                      const float* __restrict__ W,
                                                      const float* __restrict__ bias,
                                                      const float* __restrict__ W3,
                                                      const float* __restrict__ b3,
                                                      float* __restrict__ sig) {
    const int j = threadIdx.x & 127;
    const int slot = threadIdx.x >> 7;
    const int row0 = blockIdx.x * 8 + slot * 4;
    float bj = bias[j];
    float acc[4] = {bj, bj, bj, bj};
    const float* __restrict__ h0 = hin + (size_t)row0 * HH;
#pragma unroll
    for (int pass = 0; pass < 2; ++pass) {
        float wcol[64];
#pragma unroll
        for (int k = 0; k < 64; ++k) wcol[k] = W[(pass * 64 + k) * HH + j];
#pragma unroll
        for (int k = 0; k < 64; ++k) {
            int kk = pass * 64 + k;
            float w = wcol[k];
            acc[0] = fmaf(w, h0[0 * HH + kk], acc[0]);
            acc[1] = fmaf(w, h0[1 * HH + kk], acc[1]);
            acc[2] = fmaf(w, h0[2 * HH + kk], acc[2]);
            acc[3] = fmaf(w, h0[3 * HH + kk], acc[3]);
        }
    }
    // layer3: out[r][c] = b3[c] + sum_j relu(acc[r]) * W3[j][c]
    float w30 = W3[j * 3 + 0], w31 = W3[j * 3 + 1], w32 = W3[j * 3 + 2];
    __shared__ float red[2][4][2][4];   // [slot][r][wave-half][c(pad 4)]
    const int wh = (threadIdx.x >> 6) & 1;
#pragma unroll
    for (int r = 0; r < 4; ++r) {
        float h = fmaxf(acc[r], 0.f);
        float p0 = h * w30, p1 = h * w31, p2 = h * w32;
#pragma unroll
        for (int off = 32; off > 0; off >>= 1) {
            p0 += __shfl_down(p0, off);
            p1 += __shfl_down(p1, off);
            p2 += __shfl_down(p2, off);
        }
        if ((threadIdx.x & 63) == 0) {
            red[slot][r][wh][0] = p0;
            red[slot][r][wh][1] = p1;
            red[slot][r][wh][2] = p2;
        }
    }
    __syncthreads();
    if (threadIdx.x < 24) {
        int r = threadIdx.x / 3, c = threadIdx.x % 3;   // r: 0..7 block rows
        int sl = r >> 2, rr = r & 3;
        float v = red[sl][rr][0][c] + red[sl][rr][1][c] + b3[c];
        sig[(size_t)(blockIdx.x * 8 + r) * 3 + c] = __expf(v);
    }
}

// ---------------- K4: attention partials ----------------
// Block = (tg, cg): 4 waves, each wave a 32-n subchunk; lane = one target.
// P<=0 always (sig>0, squares>=0): exp(P)<=1, no max subtraction, partials sum.
__global__ __launch_bounds__(256, 4) void k_attn(const float* __restrict__ xc,
                                                 const float* __restrict__ yc,
                                                 const float* __restrict__ xt,
                                                 const float* __restrict__ sig,
                                                 float* __restrict__ pO,
                                                 float* __restrict__ pl) {
    const int tid = threadIdx.x;
    const int w = tid >> 6, lane = tid & 63;
    const int tg = blockIdx.x;      // 0..127
    const int cg = blockIdx.y;      // 0..7
    const int b = tg >> 4;
    const size_t bt = (size_t)tg * 64 + lane;   // == b*1024 + (tg&15)*64 + lane

    float s0 = sig[bt * 3 + 0], s1 = sig[bt * 3 + 1], s2 = sig[bt * 3 + 2];
    float a0 = xt[bt * 3 + 0], a1 = xt[bt * 3 + 1], a2 = xt[bt * 3 + 2];

    float acc[DYY];
#pragma unroll
    for (int d = 0; d < DYY; ++d) acc[d] = 0.f;
    float l = 0.f;

    const int n0 = cg * 128 + w * 32;
    const float* __restrict__ xcb = xc + ((size_t)b * NCC + n0) * 3;
    const float* __restrict__ ycb = yc + ((size_t)b * NCC + n0) * DYY;
#pragma unroll 4
    for (int nn = 0; nn < 32; ++nn) {
        float d0 = xcb[nn * 3 + 0] - a0;
        float d1 = xcb[nn * 3 + 1] - a1;
        float d2 = xcb[nn * 3 + 2] - a2;
        float p = fmaf(s0, d0 * d0, fmaf(s1, d1 * d1, s2 * (d2 * d2)));
        float e = __expf(-p);
        l += e;
#pragma unroll
        for (int d = 0; d < DYY; ++d) acc[d] = fmaf(e, ycb[nn * DYY + d], acc[d]);
    }

    __shared__ float ps[4 * 2048];   // [w][d*64+lane] — lanes consecutive, conflict-free
    __shared__ float pls[4 * 64];
#pragma unroll
    for (int d = 0; d < DYY; ++d) ps[w * 2048 + d * 64 + lane] = acc[d];
    pls[w * 64 + lane] = l;
    __syncthreads();

    const size_t base = ((size_t)tg * NCG + cg) * 2048;
    for (int i = tid; i < 2048; i += 256)
        pO[base + i] = ps[i] + ps[2048 + i] + ps[4096 + i] + ps[6144 + i];
    if (tid < 64)
        pl[((size_t)tg * NCG + cg) * 64 + tid] =
            pls[tid] + pls[64 + tid] + pls[128 + tid] + pls[192 + tid];
}

// ---------------- K5: combine chunk-group partials, normalize, write out ----------------
__global__ __launch_bounds__(256) void k_combine(const float* __restrict__ pO,
                                                 const float* __restrict__ pl,
                                                 float* __restrict__ out) {
    const int tg = blockIdx.x;      // 0..127
    const int tid = threadIdx.x;
    __shared__ float sm[32 * 65];   // [d][tl], stride 65 kills transpose conflicts
    __shared__ float sl[64];
    for (int i = tid; i < 2048; i += 256) {
        float s = 0.f;
#pragma unroll
        for (int c = 0; c < NCG; ++c) s += pO[((size_t)tg * NCG + c) * 2048 + i];
        sm[(i >> 6) * 65 + (i & 63)] = s;   // i = d*64+tl
    }
    if (tid < 64) {
        float lsum = 0.f;
#pragma unroll
        for (int c = 0; c < NCG; ++c) lsum += pl[((size_t)tg * NCG + c) * 64 + tid];
        sl[tid] = lsum;
    }
    __syncthreads();
    for (int i = tid; i < 2048; i += 256) {
        int tl = i >> 5, d = i & 31;
        out[(size_t)tg * 2048 + i] = sm[d * 65 + tl] / sl[tl];
    }
}

extern "C" void kernel_launch(void* const* d_in, const int* in_sizes, int n_in,
                              void* d_out, int out_size, void* d_ws, size_t ws_size,
                              hipStream_t stream) {
    const float* xc = (const float*)d_in[0];
    const float* yc = (const float*)d_in[1];
    const float* xt = (const float*)d_in[2];
    const float* W0 = (const float*)d_in[3];
    const float* b0 = (const float*)d_in[4];
    const float* W1 = (const float*)d_in[5];
    const float* b1 = (const float*)d_in[6];
    const float* W2 = (const float*)d_in[7];
    const float* b2 = (const float*)d_in[8];
    const float* W3 = (const float*)d_in[9];
    const float* b3 = (const float*)d_in[10];
    float* out = (float*)d_out;

    // workspace (floats): sig[24576] pO[2.1M] pl[64K] h1[1M] h2[1M]  ~= 17 MB
    float* ws = (float*)d_ws;
    float* sig = ws;
    float* pO = sig + (size_t)BB * NTT * 3;
    float* pl = pO + (size_t)NTG * NCG * 2048;
    float* h1 = pl + (size_t)NTG * NCG * 64;
    float* h2 = h1 + (size_t)BB * NTT * HH;

    k_layer0<<<dim3((BB * NTT * HH) / 256), dim3(256), 0, stream>>>(xt, W0, b0, h1);
    k_layer<<<dim3(1024), dim3(256), 0, stream>>>(h1, W1, b1, h2);
    k_layer2sig<<<dim3(1024), dim3(256), 0, stream>>>(h2, W2, b2, W3, b3, sig);
    k_attn<<<dim3(NTG, NCG), dim3(256), 0, stream>>>(xc, yc, xt, sig, pO, pl);
    k_combine<<<dim3(NTG), dim3(256), 0, stream>>>(pO, pl, out);
}

// Round 3
// 159.426 us; speedup vs baseline: 2.4251x; 2.4251x over previous
//
#include <hip/hip_runtime.h>
#include <math.h>

#define BB 8
#define NCC 1024
#define NTT 1024
#define HH 128
#define DYY 32
#define NCG 8                    /* n chunk-groups per batch row */
#define NTG (BB * (NTT / 64))    /* 128 target-groups of 64 */
#define LSTRIDE 129              /* padded LDS row stride (odd => conflict-free) */

// ---------------- K1: fused MLP  sig = exp(mlp(xt))  ----------------
// Block = 64 points; h lives in LDS [64][129]; wave w owns cols [w*32, w*32+32).
// W/bias indices are wave-uniform (readfirstlane) => scalar s_loads, FMA takes
// the weight as an SGPR operand. No per-thread weight arrays => no spill risk.
__global__ __launch_bounds__(256) void k_mlp(const float* __restrict__ xt,
                                             const float* __restrict__ W0,
                                             const float* __restrict__ b0,
                                             const float* __restrict__ W1,
                                             const float* __restrict__ b1,
                                             const float* __restrict__ W2,
                                             const float* __restrict__ b2,
                                             const float* __restrict__ W3,
                                             const float* __restrict__ b3,
                                             float* __restrict__ sig) {
    const int tid = threadIdx.x;
    const int lane = tid & 63;
    const int j0 = __builtin_amdgcn_readfirstlane((tid >> 6) * 32);  // wave-uniform col base
    const int row0 = blockIdx.x * 64;

    __shared__ float hbuf[64 * LSTRIDE];      // 33 KB
    __shared__ float red[4][64][4];           // L3 partials

    // ---- L0: h = relu(xt @ W0 + b0) ----
    const float* xr = xt + (size_t)(row0 + lane) * 3;
    float x0 = xr[0], x1 = xr[1], x2 = xr[2];
#pragma unroll
    for (int jj = 0; jj < 32; ++jj) {
        int j = j0 + jj;
        float a = b0[j];
        a = fmaf(x0, W0[0 * HH + j], a);
        a = fmaf(x1, W1 ? W0[1 * HH + j] : 0.f, a);   // keep simple: W0 row 1
        a = fmaf(x2, W0[2 * HH + j], a);
        hbuf[lane * LSTRIDE + j] = fmaxf(a, 0.f);
    }
    __syncthreads();

    // ---- L1, L2: h = relu(h @ W + b), in-place LDS with read/write barriers ----
    const float* Ws[2] = {W1, W2};
    const float* bs[2] = {b1, b2};
#pragma unroll
    for (int layer = 0; layer < 2; ++layer) {
        const float* __restrict__ W = Ws[layer];
        const float* __restrict__ bias = bs[layer];
        float acc[32];
#pragma unroll
        for (int jj = 0; jj < 32; ++jj) acc[jj] = bias[j0 + jj];
        for (int k = 0; k < HH; ++k) {
            float hv = hbuf[lane * LSTRIDE + k];
            const float* __restrict__ wr = W + (size_t)k * HH + j0;
#pragma unroll
            for (int jj = 0; jj < 32; ++jj) acc[jj] = fmaf(hv, wr[jj], acc[jj]);
        }
        __syncthreads();   // all reads of hbuf done
#pragma unroll
        for (int jj = 0; jj < 32; ++jj)
            hbuf[lane * LSTRIDE + j0 + jj] = fmaxf(acc[jj], 0.f);
        __syncthreads();   // writes visible before next layer reads
    }

    // ---- L3 + exp: each wave reduces its 32-col slice, combine via LDS ----
    float p0 = 0.f, p1 = 0.f, p2 = 0.f;
#pragma unroll
    for (int jj = 0; jj < 32; ++jj) {
        int j = j0 + jj;
        float h = hbuf[lane * LSTRIDE + j];
        p0 = fmaf(h, W3[j * 3 + 0], p0);
        p1 = fmaf(h, W3[j * 3 + 1], p1);
        p2 = fmaf(h, W3[j * 3 + 2], p2);
    }
    const int w = tid >> 6;
    red[w][lane][0] = p0;
    red[w][lane][1] = p1;
    red[w][lane][2] = p2;
    __syncthreads();
    if (tid < 192) {
        int r = tid / 3, c = tid - r * 3;
        float v = red[0][r][c] + red[1][r][c] + red[2][r][c] + red[3][r][c] + b3[c];
        sig[(size_t)(row0 + r) * 3 + c] = __expf(v);
    }
}

// ---------------- K2: attention partials ----------------
// Block = (tg, cg): 4 waves, each wave a 32-n subchunk; lane = one target.
// P<=0 always (sig>0, squares>=0): exp(P)<=1, no max subtraction, partials sum.
__global__ __launch_bounds__(256) void k_attn(const float* __restrict__ xc,
                                              const float* __restrict__ yc,
                                              const float* __restrict__ xt,
                                              const float* __restrict__ sig,
                                              float* __restrict__ pO,
                                              float* __restrict__ pl) {
    const int tid = threadIdx.x;
    const int w = tid >> 6, lane = tid & 63;
    const int tg = blockIdx.x;      // 0..127
    const int cg = blockIdx.y;      // 0..7
    const int b = tg >> 4;
    const size_t bt = (size_t)tg * 64 + lane;

    float s0 = sig[bt * 3 + 0], s1 = sig[bt * 3 + 1], s2 = sig[bt * 3 + 2];
    float a0 = xt[bt * 3 + 0], a1 = xt[bt * 3 + 1], a2 = xt[bt * 3 + 2];

    float acc[DYY];
#pragma unroll
    for (int d = 0; d < DYY; ++d) acc[d] = 0.f;
    float l = 0.f;

    const int n0 = cg * 128 + w * 32;
    const float* __restrict__ xcb = xc + ((size_t)b * NCC + n0) * 3;
    const float* __restrict__ ycb = yc + ((size_t)b * NCC + n0) * DYY;
#pragma unroll 4
    for (int nn = 0; nn < 32; ++nn) {
        float d0 = xcb[nn * 3 + 0] - a0;
        float d1 = xcb[nn * 3 + 1] - a1;
        float d2 = xcb[nn * 3 + 2] - a2;
        float p = fmaf(s0, d0 * d0, fmaf(s1, d1 * d1, s2 * (d2 * d2)));
        float e = __expf(-p);
        l += e;
#pragma unroll
        for (int d = 0; d < DYY; ++d) acc[d] = fmaf(e, ycb[nn * DYY + d], acc[d]);
    }

    __shared__ float ps[4 * 2048];   // [w][d*64+lane] — lanes consecutive, conflict-free
    __shared__ float pls[4 * 64];
#pragma unroll
    for (int d = 0; d < DYY; ++d) ps[w * 2048 + d * 64 + lane] = acc[d];
    pls[w * 64 + lane] = l;
    __syncthreads();

    const size_t base = ((size_t)tg * NCG + cg) * 2048;
    for (int i = tid; i < 2048; i += 256)
        pO[base + i] = ps[i] + ps[2048 + i] + ps[4096 + i] + ps[6144 + i];
    if (tid < 64)
        pl[((size_t)tg * NCG + cg) * 64 + tid] =
            pls[tid] + pls[64 + tid] + pls[128 + tid] + pls[192 + tid];
}

// ---------------- K3: combine chunk-group partials, normalize, write out ----------------
__global__ __launch_bounds__(256) void k_combine(const float* __restrict__ pO,
                                                 const float* __restrict__ pl,
                                                 float* __restrict__ out) {
    const int tg = blockIdx.x;      // 0..127
    const int tid = threadIdx.x;
    __shared__ float sm[32 * 65];   // [d][tl], stride 65 kills transpose conflicts
    __shared__ float sl[64];
    for (int i = tid; i < 2048; i += 256) {
        float s = 0.f;
#pragma unroll
        for (int c = 0; c < NCG; ++c) s += pO[((size_t)tg * NCG + c) * 2048 + i];
        sm[(i >> 6) * 65 + (i & 63)] = s;   // i = d*64+tl
    }
    if (tid < 64) {
        float lsum = 0.f;
#pragma unroll
        for (int c = 0; c < NCG; ++c) lsum += pl[((size_t)tg * NCG + c) * 64 + tid];
        sl[tid] = lsum;
    }
    __syncthreads();
    for (int i = tid; i < 2048; i += 256) {
        int tl = i >> 5, d = i & 31;
        out[(size_t)tg * 2048 + i] = sm[d * 65 + tl] / sl[tl];
    }
}

extern "C" void kernel_launch(void* const* d_in, const int* in_sizes, int n_in,
                              void* d_out, int out_size, void* d_ws, size_t ws_size,
                              hipStream_t stream) {
    const float* xc = (const float*)d_in[0];
    const float* yc = (const float*)d_in[1];
    const float* xt = (const float*)d_in[2];
    const float* W0 = (const float*)d_in[3];
    const float* b0 = (const float*)d_in[4];
    const float* W1 = (const float*)d_in[5];
    const float* b1 = (const float*)d_in[6];
    const float* W2 = (const float*)d_in[7];
    const float* b2 = (const float*)d_in[8];
    const float* W3 = (const float*)d_in[9];
    const float* b3 = (const float*)d_in[10];
    float* out = (float*)d_out;

    // workspace (floats): sig[24576] pO[2.1M] pl[64K]  ~= 8.8 MB
    float* ws = (float*)d_ws;
    float* sig = ws;
    float* pO = sig + (size_t)BB * NTT * 3;
    float* pl = pO + (size_t)NTG * NCG * 2048;

    k_mlp<<<dim3(BB * NTT / 64), dim3(256), 0, stream>>>(xt, W0, b0, W1, b1, W2, b2,
                                                         W3, b3, sig);
    k_attn<<<dim3(NTG, NCG), dim3(256), 0, stream>>>(xc, yc, xt, sig, pO, pl);
    k_combine<<<dim3(NTG), dim3(256), 0, stream>>>(pO, pl, out);
}

// Round 4
// 147.683 us; speedup vs baseline: 2.6179x; 1.0795x over previous
//
#include <hip/hip_runtime.h>
#include <math.h>

#define BB 8
#define NCC 1024
#define NTT 1024
#define HH 128
#define DYY 32
#define NCG 8                    /* n chunk-groups per batch row */
#define NTG (BB * (NTT / 64))    /* 128 target-groups of 64 */
#define HSTRIDE 132              /* hbuf row stride: mult of 4 (16B align), 132%32=4 -> conflict-free */

// ---------------- K1: fused MLP  sig = exp(mlp(xt))  ----------------
// 256 blocks x 512 threads; block = 32 points. thread = (p = tid>>4, jg = tid&15),
// owns 8 output cols [jg*8, jg*8+8) of point p. h tiles live in LDS [32][132].
// W read per-lane as float4 (vmcnt-pipelined, L1 broadcast across the 32
// threads sharing jg). No s_loads and no big per-thread arrays in the loop.
__global__ __launch_bounds__(512) void k_mlp(const float* __restrict__ xt,
                                             const float* __restrict__ W0,
                                             const float* __restrict__ b0,
                                             const float* __restrict__ W1,
                                             const float* __restrict__ b1,
                                             const float* __restrict__ W2,
                                             const float* __restrict__ b2,
                                             const float* __restrict__ W3,
                                             const float* __restrict__ b3,
                                             float* __restrict__ sig) {
    const int tid = threadIdx.x;
    const int p = tid >> 4;         // 0..31  point within block
    const int jg = tid & 15;        // 0..15  col-group
    const int j0 = jg * 8;
    const int row0 = blockIdx.x * 32;

    __shared__ __align__(16) float hbuf[32 * HSTRIDE];   // 16.9 KB
    __shared__ float red[32 * 16 * 3];                   // L3 partials, 6 KB

    // ---- L0: o = relu(xt @ W0 + b0) for my (p, 8 cols) ----
    const float* xr = xt + (size_t)(row0 + p) * 3;
    float x0 = xr[0], x1 = xr[1], x2 = xr[2];
    float o[8];
#pragma unroll
    for (int jj = 0; jj < 8; ++jj) {
        int j = j0 + jj;
        float a = b0[j];
        a = fmaf(x0, W0[0 * HH + j], a);
        a = fmaf(x1, W0[1 * HH + j], a);
        a = fmaf(x2, W0[2 * HH + j], a);
        o[jj] = fmaxf(a, 0.f);
    }
#pragma unroll
    for (int jj = 0; jj < 8; ++jj) hbuf[p * HSTRIDE + j0 + jj] = o[jj];
    __syncthreads();

    // ---- L1, L2: o = relu(h @ W + b) ----
    for (int l = 0; l < 2; ++l) {
        const float* __restrict__ W = (l == 0) ? W1 : W2;
        const float* __restrict__ bi = (l == 0) ? b1 : b2;
        const float4* __restrict__ Wv = (const float4*)W;   // [k][32 float4]
        float acc[8];
#pragma unroll
        for (int jj = 0; jj < 8; ++jj) acc[jj] = bi[j0 + jj];
#pragma unroll 16
        for (int k = 0; k < HH; ++k) {
            float hv = hbuf[p * HSTRIDE + k];
            float4 wa = Wv[k * 32 + jg * 2];
            float4 wb = Wv[k * 32 + jg * 2 + 1];
            acc[0] = fmaf(hv, wa.x, acc[0]);
            acc[1] = fmaf(hv, wa.y, acc[1]);
            acc[2] = fmaf(hv, wa.z, acc[2]);
            acc[3] = fmaf(hv, wa.w, acc[3]);
            acc[4] = fmaf(hv, wb.x, acc[4]);
            acc[5] = fmaf(hv, wb.y, acc[5]);
            acc[6] = fmaf(hv, wb.z, acc[6]);
            acc[7] = fmaf(hv, wb.w, acc[7]);
        }
        __syncthreads();        // all reads of hbuf complete
#pragma unroll
        for (int jj = 0; jj < 8; ++jj) o[jj] = fmaxf(acc[jj], 0.f);
        if (l == 0) {
#pragma unroll
            for (int jj = 0; jj < 8; ++jj) hbuf[p * HSTRIDE + j0 + jj] = o[jj];
            __syncthreads();
        }
    }

    // ---- L3 + exp: partial over my 8 cols, reduce across the 16 jg threads ----
    float p0 = 0.f, p1 = 0.f, p2 = 0.f;
#pragma unroll
    for (int jj = 0; jj < 8; ++jj) {
        int j = j0 + jj;
        p0 = fmaf(o[jj], W3[j * 3 + 0], p0);
        p1 = fmaf(o[jj], W3[j * 3 + 1], p1);
        p2 = fmaf(o[jj], W3[j * 3 + 2], p2);
    }
    red[(p * 16 + jg) * 3 + 0] = p0;
    red[(p * 16 + jg) * 3 + 1] = p1;
    red[(p * 16 + jg) * 3 + 2] = p2;
    __syncthreads();
    if (tid < 96) {
        int r = tid / 3, c = tid - r * 3;
        float v = b3[c];
#pragma unroll
        for (int g = 0; g < 16; ++g) v += red[(r * 16 + g) * 3 + c];
        sig[(size_t)(row0 + r) * 3 + c] = __expf(v);
    }
}

// ---------------- K2: attention partials ----------------
// Block = (tg, cg): 4 waves, each wave a 32-n subchunk; lane = one target.
// P<=0 always (sig>0, squares>=0): exp(P)<=1, no max subtraction, partials sum.
__global__ __launch_bounds__(256) void k_attn(const float* __restrict__ xc,
                                              const float* __restrict__ yc,
                                              const float* __restrict__ xt,
                                              const float* __restrict__ sig,
                                              float* __restrict__ pO,
                                              float* __restrict__ pl) {
    const int tid = threadIdx.x;
    const int w = tid >> 6, lane = tid & 63;
    const int tg = blockIdx.x;      // 0..127
    const int cg = blockIdx.y;      // 0..7
    const int b = tg >> 4;
    const size_t bt = (size_t)tg * 64 + lane;

    float s0 = sig[bt * 3 + 0], s1 = sig[bt * 3 + 1], s2 = sig[bt * 3 + 2];
    float a0 = xt[bt * 3 + 0], a1 = xt[bt * 3 + 1], a2 = xt[bt * 3 + 2];

    float acc[DYY];
#pragma unroll
    for (int d = 0; d < DYY; ++d) acc[d] = 0.f;
    float l = 0.f;

    const int n0 = cg * 128 + w * 32;
    const float* __restrict__ xcb = xc + ((size_t)b * NCC + n0) * 3;
    const float* __restrict__ ycb = yc + ((size_t)b * NCC + n0) * DYY;
#pragma unroll 4
    for (int nn = 0; nn < 32; ++nn) {
        float d0 = xcb[nn * 3 + 0] - a0;
        float d1 = xcb[nn * 3 + 1] - a1;
        float d2 = xcb[nn * 3 + 2] - a2;
        float p = fmaf(s0, d0 * d0, fmaf(s1, d1 * d1, s2 * (d2 * d2)));
        float e = __expf(-p);
        l += e;
#pragma unroll
        for (int d = 0; d < DYY; ++d) acc[d] = fmaf(e, ycb[nn * DYY + d], acc[d]);
    }

    __shared__ float ps[4 * 2048];   // [w][d*64+lane] — lanes consecutive, conflict-free
    __shared__ float pls[4 * 64];
#pragma unroll
    for (int d = 0; d < DYY; ++d) ps[w * 2048 + d * 64 + lane] = acc[d];
    pls[w * 64 + lane] = l;
    __syncthreads();

    const size_t base = ((size_t)tg * NCG + cg) * 2048;
    for (int i = tid; i < 2048; i += 256)
        pO[base + i] = ps[i] + ps[2048 + i] + ps[4096 + i] + ps[6144 + i];
    if (tid < 64)
        pl[((size_t)tg * NCG + cg) * 64 + tid] =
            pls[tid] + pls[64 + tid] + pls[128 + tid] + pls[192 + tid];
}

// ---------------- K3: combine chunk-group partials, normalize, write out ----------------
__global__ __launch_bounds__(256) void k_combine(const float* __restrict__ pO,
                                                 const float* __restrict__ pl,
                                                 float* __restrict__ out) {
    const int tg = blockIdx.x;      // 0..127
    const int tid = threadIdx.x;
    __shared__ float sm[32 * 65];   // [d][tl], stride 65 kills transpose conflicts
    __shared__ float sl[64];
    for (int i = tid; i < 2048; i += 256) {
        float s = 0.f;
#pragma unroll
        for (int c = 0; c < NCG; ++c) s += pO[((size_t)tg * NCG + c) * 2048 + i];
        sm[(i >> 6) * 65 + (i & 63)] = s;   // i = d*64+tl
    }
    if (tid < 64) {
        float lsum = 0.f;
#pragma unroll
        for (int c = 0; c < NCG; ++c) lsum += pl[((size_t)tg * NCG + c) * 64 + tid];
        sl[tid] = lsum;
    }
    __syncthreads();
    for (int i = tid; i < 2048; i += 256) {
        int tl = i >> 5, d = i & 31;
        out[(size_t)tg * 2048 + i] = sm[d * 65 + tl] / sl[tl];
    }
}

extern "C" void kernel_launch(void* const* d_in, const int* in_sizes, int n_in,
                              void* d_out, int out_size, void* d_ws, size_t ws_size,
                              hipStream_t stream) {
    const float* xc = (const float*)d_in[0];
    const float* yc = (const float*)d_in[1];
    const float* xt = (const float*)d_in[2];
    const float* W0 = (const float*)d_in[3];
    const float* b0 = (const float*)d_in[4];
    const float* W1 = (const float*)d_in[5];
    const float* b1 = (const float*)d_in[6];
    const float* W2 = (const float*)d_in[7];
    const float* b2 = (const float*)d_in[8];
    const float* W3 = (const float*)d_in[9];
    const float* b3 = (const float*)d_in[10];
    float* out = (float*)d_out;

    // workspace (floats): sig[24576] pO[2.1M] pl[64K]  ~= 8.8 MB
    float* ws = (float*)d_ws;
    float* sig = ws;
    float* pO = sig + (size_t)BB * NTT * 3;
    float* pl = pO + (size_t)NTG * NCG * 2048;

    k_mlp<<<dim3(BB * NTT / 32), dim3(512), 0, stream>>>(xt, W0, b0, W1, b1, W2, b2,
                                                         W3, b3, sig);
    k_attn<<<dim3(NTG, NCG), dim3(256), 0, stream>>>(xc, yc, xt, sig, pO, pl);
    k_combine<<<dim3(NTG), dim3(256), 0, stream>>>(pO, pl, out);
}